// Round 5
// baseline (243.340 us; speedup 1.0000x reference)
//
#include <hip/hip_runtime.h>

#define SEQ  2048
#define HID  128
#define NB   32
#define TILE 58            // owned rows per block
#define ROWS 64            // staged rows: lane <-> m, s = s0-3+lane
#define GX   36            // ceil(2048/58)
#define HSTR 132           // hbuf row stride (floats): 4-bank lane step, b128-clean

typedef float f2 __attribute__((ext_vector_type(2)));
typedef float f4 __attribute__((ext_vector_type(4)));

// Force a pointer into SGPRs (wave-uniform) so uniform-indexed loads select SMEM.
__device__ __forceinline__ const float* uptr(const float* p) {
  unsigned long long v = (unsigned long long)p;
  unsigned lo = __builtin_amdgcn_readfirstlane((unsigned)v);
  unsigned hi = __builtin_amdgcn_readfirstlane((unsigned)(v >> 32));
  return (const float*)((((unsigned long long)hi) << 32) | lo);
}

// acc[0..15] (f2 pairs, 32 cols) += A * W_row[32 cols]; packed fp32 (v_pk_fma_f32)
__device__ __forceinline__ void step32(const f4* W, float A, f2* acc) {
  const f2 av = {A, A};
  #pragma unroll
  for (int q = 0; q < 8; ++q) {
    acc[2 * q]     += av * (f2){W[q].x, W[q].y};
    acc[2 * q + 1] += av * (f2){W[q].z, W[q].w};
  }
}

__device__ __forceinline__ void loadw(const float* Wu, int k, f4* W) {
  const f4* p = (const f4*)(Wu + k * HID);
  #pragma unroll
  for (int q = 0; q < 8; ++q) W[q] = p[q];
}

// ---------------------------------------------------------------------------
// Fused enc1 -> enc2 -> gc1 -> gc2 -> gc3 -> per-block pool partials.
// lane (0..63) = staged activation row m; wave (0..3) = 32-col group c0=wv*32.
// W rows stream through SGPRs (uniform s_load, ping-pong); A via ds_read_b64;
// tridiagonal aggregate via __shfl (rows are lanes). Validity telescoping:
// enc valid m in [0,63] -> gc1 [1,62] -> gc2 [2,61] -> gc3 [3,60] = owned.
// Out-of-sequence rows are zero-masked at each gc's t (reference zero-pad).
// No global stores before the last load -> SMEM-legal; no atomics/memset.
// ---------------------------------------------------------------------------
__global__ __launch_bounds__(256) void fused_kernel(
    const float* __restrict__ x,
    const float* __restrict__ enc_w1, const float* __restrict__ enc_b1,
    const float* __restrict__ enc_w2, const float* __restrict__ enc_b2,
    const float* __restrict__ gc1_w, const float* __restrict__ gc1_b,
    const float* __restrict__ gc2_w, const float* __restrict__ gc2_b,
    const float* __restrict__ gc3_w, const float* __restrict__ gc3_b,
    float* __restrict__ partial)
{
  __shared__ __align__(16) float hbuf[ROWS * HSTR];    // 33792 B
  __shared__ __align__(16) float wsmall[7 * HID];      // enc_w1 (6x128) + enc_b1
  __shared__ float psum[256];

  const int tid  = threadIdx.x;
  const int lane = tid & 63;
  const int c0   = __builtin_amdgcn_readfirstlane((tid >> 6) << 5);
  const int gx   = blockIdx.x, b = blockIdx.y;
  const int s0   = gx * TILE;
  const int s    = s0 - 3 + lane;
  const bool inseq = (s >= 0 && s < SEQ);

  // ---------------- stage enc_w1 + enc_b1 ----------------
  for (int f = tid; f < 7 * HID; f += 256)
    wsmall[f] = (f < 6 * HID) ? enc_w1[f] : enc_b1[f - 6 * HID];

  // per-lane x row (zero outside sequence)
  float xv[6];
  if (inseq) {
    const f2* xp = (const f2*)(x + ((long long)b * SEQ + s) * 6);
    const f2 x0 = xp[0], x1 = xp[1], x2 = xp[2];
    xv[0] = x0.x; xv[1] = x0.y; xv[2] = x1.x;
    xv[3] = x1.y; xv[4] = x2.x; xv[5] = x2.y;
  } else {
    #pragma unroll
    for (int k = 0; k < 6; ++k) xv[k] = 0.f;
  }
  __syncthreads();

  f2 acc[16];

  // ---------------- enc1: h1 = relu(x @ w1 + b1) -> hbuf ----------------
  #pragma unroll
  for (int q = 0; q < 16; ++q) acc[q] = (f2){0.f, 0.f};
  #pragma unroll
  for (int k = 0; k < 6; ++k) {
    const f4* wp = (const f4*)&wsmall[k * HID + c0];   // broadcast LDS reads
    f4 W[8];
    #pragma unroll
    for (int q = 0; q < 8; ++q) W[q] = wp[q];
    step32(W, xv[k], acc);
  }
  {
    const float* b1s = wsmall + 6 * HID;
    #pragma unroll
    for (int q = 0; q < 8; ++q) {
      const f4 bb = *(const f4*)&b1s[c0 + q * 4];
      f4 o = { fmaxf(acc[2*q].x   + bb.x, 0.f), fmaxf(acc[2*q].y   + bb.y, 0.f),
               fmaxf(acc[2*q+1].x + bb.z, 0.f), fmaxf(acc[2*q+1].y + bb.w, 0.f) };
      *(f4*)&hbuf[lane * HSTR + c0 + q * 4] = o;
    }
  }

  // ---------------- 4 x (128-K GEMM [+ tridiag agg + relu]) ----------------
  for (int L = 0; L < 4; ++L) {
    const float* Wg = (L == 0) ? enc_w2 : (L == 1) ? gc1_w
                    : (L == 2) ? gc2_w  : gc3_w;
    const float* bg = (L == 0) ? enc_b2 : (L == 1) ? gc1_b
                    : (L == 2) ? gc2_b  : gc3_b;
    const float* Wu = uptr(Wg) + c0;

    __syncthreads();            // hbuf writes (enc1 / prev epilogue) visible

    f4 wa[8], wb[8];
    loadw(Wu, 0, wa);
    #pragma unroll
    for (int q = 0; q < 16; ++q) acc[q] = (f2){0.f, 0.f};

    #pragma unroll 1
    for (int k2 = 0; k2 < 64; ++k2) {
      const int k = k2 * 2;
      const f2 a2 = *(const f2*)&hbuf[lane * HSTR + k];
      loadw(Wu, k + 1, wb);                    // prefetch row k+1
      step32(wa, a2.x, acc);
      loadw(Wu, (k2 < 63) ? k + 2 : 126, wa);  // prefetch row k+2 (guarded)
      step32(wb, a2.y, acc);
    }
    __syncthreads();            // all hbuf reads of this layer done

    const float* bu = uptr(bg) + c0;
    f4 bb[8];
    #pragma unroll
    for (int q = 0; q < 8; ++q) bb[q] = *(const f4*)&bu[q * 4];

    if (L == 0) {
      // enc2: h = acc + b2 (no relu, no mask) -> hbuf
      #pragma unroll
      for (int q = 0; q < 8; ++q) {
        f4 o = { acc[2*q].x   + bb[q].x, acc[2*q].y   + bb[q].y,
                 acc[2*q+1].x + bb[q].z, acc[2*q+1].y + bb[q].w };
        *(f4*)&hbuf[lane * HSTR + c0 + q * 4] = o;
      }
    } else {
      // t = inseq ? acc + b : 0, then in-lane tridiagonal aggregate + relu
      f2 t[16];
      #pragma unroll
      for (int q = 0; q < 8; ++q) {
        f2 t0 = acc[2*q]     + (f2){bb[q].x, bb[q].y};
        f2 t1 = acc[2*q + 1] + (f2){bb[q].z, bb[q].w};
        if (!inseq) { t0 = (f2){0.f, 0.f}; t1 = (f2){0.f, 0.f}; }
        t[2*q] = t0; t[2*q + 1] = t1;
      }
      const float invd = (s == 0 || s == SEQ - 1) ? (1.0f / (2.0f + 1e-8f))
                                                  : (1.0f / (3.0f + 1e-8f));
      #pragma unroll
      for (int q = 0; q < 16; ++q) {
        const float lx = __shfl_up(t[q].x, 1);
        const float ly = __shfl_up(t[q].y, 1);
        const float rx = __shfl_down(t[q].x, 1);
        const float ry = __shfl_down(t[q].y, 1);
        t[q].x = fmaxf((lx + t[q].x + rx) * invd, 0.f);
        t[q].y = fmaxf((ly + t[q].y + ry) * invd, 0.f);
      }
      #pragma unroll
      for (int q = 0; q < 8; ++q)
        *(f4*)&hbuf[lane * HSTR + c0 + q * 4] =
            (f4){t[2*q].x, t[2*q].y, t[2*q+1].x, t[2*q+1].y};
    }
  }

  // ---------------- pool: per-block partial sums (owned rows m=3..60) -------
  __syncthreads();
  {
    const int c = tid & 127, g2 = tid >> 7;
    float ps = 0.f;
    #pragma unroll 1
    for (int r = 0; r < 29; ++r) {
      const int m  = 3 + g2 * 29 + r;
      const int ss = s0 + g2 * 29 + r;
      if (ss < SEQ) ps += hbuf[m * HSTR + c];
    }
    psum[tid] = ps;
  }
  __syncthreads();
  if (tid < 128)
    partial[((long long)b * GX + gx) * HID + tid] = psum[tid] + psum[tid + 128];
}

// ---------------------------------------------------------------------------
// Classifier: reduce partials -> mean -> relu(mean@w1+b1)@w2+b2
// ---------------------------------------------------------------------------
__global__ __launch_bounds__(128) void cls_kernel(
    const float* __restrict__ partial,
    const float* __restrict__ w1, const float* __restrict__ b1,
    const float* __restrict__ w2, const float* __restrict__ b2,
    float* __restrict__ out)
{
  __shared__ float ms[128];
  __shared__ float hid[64];
  const int b = blockIdx.x, tid = threadIdx.x;
  float a = 0.f;
  #pragma unroll 1
  for (int g = 0; g < GX; ++g) a += partial[((long long)b * GX + g) * HID + tid];
  ms[tid] = a * (1.0f / 2048.0f);
  __syncthreads();
  if (tid < 64) {
    float h = b1[tid];
    for (int k = 0; k < 128; ++k) h = fmaf(ms[k], w1[k * 64 + tid], h);
    hid[tid] = fmaxf(h, 0.f);
  }
  __syncthreads();
  if (tid < 3) {
    float o = b2[tid];
    for (int k = 0; k < 64; ++k) o = fmaf(hid[k], w2[k * 3 + tid], o);
    out[b * 3 + tid] = o;
  }
}

extern "C" void kernel_launch(void* const* d_in, const int* in_sizes, int n_in,
                              void* d_out, int out_size, void* d_ws, size_t ws_size,
                              hipStream_t stream) {
  (void)in_sizes; (void)n_in; (void)out_size; (void)ws_size;
  const float* x      = (const float*)d_in[0];
  const float* enc_w1 = (const float*)d_in[1];
  const float* enc_b1 = (const float*)d_in[2];
  const float* enc_w2 = (const float*)d_in[3];
  const float* enc_b2 = (const float*)d_in[4];
  const float* gc1_w  = (const float*)d_in[5];
  const float* gc1_b  = (const float*)d_in[6];
  const float* gc2_w  = (const float*)d_in[7];
  const float* gc2_b  = (const float*)d_in[8];
  const float* gc3_w  = (const float*)d_in[9];
  const float* gc3_b  = (const float*)d_in[10];
  const float* cls_w1 = (const float*)d_in[11];
  const float* cls_b1 = (const float*)d_in[12];
  const float* cls_w2 = (const float*)d_in[13];
  const float* cls_b2 = (const float*)d_in[14];

  float* partial = (float*)d_ws;   // [NB][GX][HID], every slot written each call

  fused_kernel<<<dim3(GX, NB), 256, 0, stream>>>(
      x, enc_w1, enc_b1, enc_w2, enc_b2,
      gc1_w, gc1_b, gc2_w, gc2_b, gc3_w, gc3_b, partial);
  cls_kernel<<<dim3(NB), 128, 0, stream>>>(partial, cls_w1, cls_b1, cls_w2, cls_b2,
                                           (float*)d_out);
}

// Round 6
// 147.399 us; speedup vs baseline: 1.6509x; 1.6509x over previous
//
#include <hip/hip_runtime.h>

#define SEQ  2048
#define HID  128
#define NB   32
#define TILE 58            // owned output rows per block
#define GX   36            // ceil(2048/58)
#define MSTR 67            // hT row stride: hT[k][m], k=0..127, m=0..63 (+pad)

typedef float f2    __attribute__((ext_vector_type(2)));
typedef float f32x4 __attribute__((ext_vector_type(4)));
typedef short bf16x8 __attribute__((ext_vector_type(8)));

// split v into bf16 hi + bf16 lo (RNE both); v ~= hi + lo to ~16 mantissa bits
__device__ __forceinline__ void split_bf16(float v, short& h, short& l) {
  unsigned u = __float_as_uint(v);
  unsigned r = (u + 0x7fffu + ((u >> 16) & 1u)) >> 16;
  h = (short)r;
  const float hf = __uint_as_float(r << 16);
  const float lo = v - hf;
  unsigned u2 = __float_as_uint(lo);
  unsigned r2 = (u2 + 0x7fffu + ((u2 >> 16) & 1u)) >> 16;
  l = (short)r2;
}

// ---------------------------------------------------------------------------
// prep_fold: W' = enc_w2 @ gc1_w (128x128), b' = enc_b2 @ gc1_w + gc1_b.
// Legal because there is no nonlinearity between enc2 and gc1's matmul.
// ---------------------------------------------------------------------------
__global__ __launch_bounds__(256) void prep_fold(
    const float* __restrict__ enc_w2, const float* __restrict__ enc_b2,
    const float* __restrict__ gc1_w, const float* __restrict__ gc1_b,
    float* __restrict__ Wp, float* __restrict__ bp)
{
  const int tid = threadIdx.x;
  if (blockIdx.x < 16) {
    const int r = blockIdx.x * 8 + (tid >> 5);
    const int c = (tid & 31) * 4;
    float4 a = make_float4(0.f, 0.f, 0.f, 0.f);
    for (int k = 0; k < 128; ++k) {
      const float w = enc_w2[r * 128 + k];
      const float4 g = *(const float4*)&gc1_w[k * 128 + c];
      a.x = fmaf(w, g.x, a.x); a.y = fmaf(w, g.y, a.y);
      a.z = fmaf(w, g.z, a.z); a.w = fmaf(w, g.w, a.w);
    }
    *(float4*)&Wp[r * 128 + c] = a;
  } else if (tid < 128) {
    float s = gc1_b[tid];
    for (int k = 0; k < 128; ++k) s = fmaf(enc_b2[k], gc1_w[k * 128 + tid], s);
    bp[tid] = s;
  }
}

// ---------------------------------------------------------------------------
// prep_shuffle: split each layer weight (W', gc2_w, gc3_w) into bf16 hi/lo and
// lay out in MFMA B-fragment order for 16x16x32:
//   frag(ks,nt): lane l, elem j  <->  W[k = ks*32 + (l>>4)*8 + j][n = nt*16 + (l&15)]
//   dest index = (((ks*8 + nt)*64 + l)*8 + j); hi at Wf+L*32768, lo at +16384.
// ---------------------------------------------------------------------------
__global__ __launch_bounds__(256) void prep_shuffle(
    const float* __restrict__ Wp, const float* __restrict__ gc2_w,
    const float* __restrict__ gc3_w, short* __restrict__ Wf)
{
  const int L = blockIdx.y;
  const float* SW = (L == 0) ? Wp : (L == 1) ? gc2_w : gc3_w;
  const int ks = blockIdx.x >> 3, nt = blockIdx.x & 7;
  short* hi = Wf + L * 32768;
  short* lo = hi + 16384;
  for (int f = threadIdx.x; f < 512; f += 256) {
    const int l = f >> 3, j = f & 7;
    const int k = ks * 32 + (l >> 4) * 8 + j;
    const int n = nt * 16 + (l & 15);
    short h, lw;
    split_bf16(SW[k * 128 + n], h, lw);
    const int d = ((ks * 8 + nt) * 64 + l) * 8 + j;
    hi[d] = h; lo[d] = lw;
  }
}

// ---------------------------------------------------------------------------
// Fused enc1 -> [enc2*gc1 folded] -> gc2 -> gc3 -> pool partials, MFMA bf16x3.
// Block = (58-row seq tile, batch), 256 thr = 4 waves; wave w owns rows
// m = w*16 .. w*16+15 of the 64 staged rows (s = s0-3+m).
// Activations in transposed LDS hT[k][m] (all scalar b32, <=2-way banks).
// A-frag assembly folds tridiag-aggregate + relu + bf16 hi/lo split.
// Epilogue scatters C/D frags (col=lane&15, row=quad*4+reg) back to hT.
// Validity telescoping: t1 ok m in [0,63]&inseq -> h1 [1,62] -> h2 [2,61]
// -> t3 ok [2,61] -> pooled rows m in [3,60] need t3[m-1..m+1] in [2,61]. OK.
// ---------------------------------------------------------------------------
__global__ __launch_bounds__(256) void fused_kernel(
    const float* __restrict__ x,
    const float* __restrict__ enc_w1, const float* __restrict__ enc_b1,
    const short* __restrict__ Wf, const float* __restrict__ bp,
    const float* __restrict__ gc2_b, const float* __restrict__ gc3_b,
    float* __restrict__ partial)
{
  __shared__ float hT[HID * MSTR];      // 34304 B, [k][m]
  __shared__ float wsmall[7 * HID];     // enc_w1 (6x128) + enc_b1
  __shared__ float psum[256];

  const int tid  = threadIdx.x;
  const int lane = tid & 63;
  const int w    = tid >> 6;            // wave id 0..3
  const int gxb  = blockIdx.x, b = blockIdx.y;
  const int s0   = gxb * TILE;

  // ---------------- enc1 (fp32 VALU): lane = row m, wave = 32-col group ----
  for (int f = tid; f < 7 * HID; f += 256)
    wsmall[f] = (f < 6 * HID) ? enc_w1[f] : enc_b1[f - 6 * HID];

  const int sm = s0 - 3 + lane;
  float xv[6];
  if (sm >= 0 && sm < SEQ) {
    const f2* xp = (const f2*)(x + ((long long)b * SEQ + sm) * 6);
    const f2 a0 = xp[0], a1 = xp[1], a2 = xp[2];
    xv[0] = a0.x; xv[1] = a0.y; xv[2] = a1.x;
    xv[3] = a1.y; xv[4] = a2.x; xv[5] = a2.y;
  } else {
    #pragma unroll
    for (int k = 0; k < 6; ++k) xv[k] = 0.f;
  }
  __syncthreads();
  {
    const int c0 = w * 32;
    float4 a4[8];
    #pragma unroll
    for (int q = 0; q < 8; ++q) a4[q] = make_float4(0.f, 0.f, 0.f, 0.f);
    #pragma unroll
    for (int k = 0; k < 6; ++k) {
      #pragma unroll
      for (int q = 0; q < 8; ++q) {
        const float4 wv = *(const float4*)&wsmall[k * HID + c0 + q * 4];
        a4[q].x = fmaf(xv[k], wv.x, a4[q].x);
        a4[q].y = fmaf(xv[k], wv.y, a4[q].y);
        a4[q].z = fmaf(xv[k], wv.z, a4[q].z);
        a4[q].w = fmaf(xv[k], wv.w, a4[q].w);
      }
    }
    #pragma unroll
    for (int q = 0; q < 8; ++q) {
      const float4 bb = *(const float4*)&wsmall[6 * HID + c0 + q * 4];
      const int c = c0 + q * 4;
      hT[(c + 0) * MSTR + lane] = fmaxf(a4[q].x + bb.x, 0.f);
      hT[(c + 1) * MSTR + lane] = fmaxf(a4[q].y + bb.y, 0.f);
      hT[(c + 2) * MSTR + lane] = fmaxf(a4[q].z + bb.z, 0.f);
      hT[(c + 3) * MSTR + lane] = fmaxf(a4[q].w + bb.w, 0.f);
    }
  }
  __syncthreads();

  // ---------------- 3 MFMA layers ----------------
  const int mt   = w * 16 + (lane & 15);       // A-frag target row
  const int koct = (lane >> 4) * 8;            // A-frag k-octet base
  const int stt  = s0 - 3 + mt;
  const float invdA = (stt == 0 || stt == SEQ - 1) ? (1.0f / (2.0f + 1e-8f))
                                                   : (1.0f / (3.0f + 1e-8f));
  const int mm = (mt == 0) ? 0 : mt - 1;
  const int mp = (mt == 63) ? 63 : mt + 1;

  #pragma unroll 1
  for (int L = 0; L < 3; ++L) {
    const short* WfL = Wf + L * 32768;
    const bf16x8* Bhi = (const bf16x8*)WfL;
    const bf16x8* Blo = (const bf16x8*)(WfL + 16384);
    const float* bias = (L == 0) ? bp : (L == 1) ? gc2_b : gc3_b;

    f32x4 acc[8];
    #pragma unroll
    for (int nt = 0; nt < 8; ++nt) acc[nt] = (f32x4){0.f, 0.f, 0.f, 0.f};

    #pragma unroll 1
    for (int ks = 0; ks < 4; ++ks) {
      // B-frags first (VMEM latency hides behind A assembly)
      const int fb = ks * 512 + lane;
      bf16x8 bh[8], bl[8];
      #pragma unroll
      for (int nt = 0; nt < 8; ++nt) {
        bh[nt] = Bhi[fb + nt * 64];
        bl[nt] = Blo[fb + nt * 64];
      }
      // A-frag: read hT (agg+relu for L>0), split hi/lo
      bf16x8 ah, al;
      const float* pa = &hT[(ks * 32 + koct) * MSTR];
      #pragma unroll
      for (int j = 0; j < 8; ++j) {
        float v;
        if (L == 0) {
          v = pa[j * MSTR + mt];
        } else {
          v = (pa[j * MSTR + mm] + pa[j * MSTR + mt] + pa[j * MSTR + mp]) * invdA;
          v = fmaxf(v, 0.f);
        }
        short h, lo;
        split_bf16(v, h, lo);
        ah[j] = h; al[j] = lo;
      }
      #pragma unroll
      for (int nt = 0; nt < 8; ++nt) {
        acc[nt] = __builtin_amdgcn_mfma_f32_16x16x32_bf16(ah, bh[nt], acc[nt], 0, 0, 0);
        acc[nt] = __builtin_amdgcn_mfma_f32_16x16x32_bf16(ah, bl[nt], acc[nt], 0, 0, 0);
        acc[nt] = __builtin_amdgcn_mfma_f32_16x16x32_bf16(al, bh[nt], acc[nt], 0, 0, 0);
      }
    }
    __syncthreads();   // all hT reads of this layer done

    // epilogue: t = inseq ? acc + bias : 0 -> hT[n][m]  (C/D layout scatter)
    {
      const int n0 = lane & 15;
      const int mrow0 = w * 16 + (lane >> 4) * 4;
      #pragma unroll
      for (int nt = 0; nt < 8; ++nt) {
        const float bn = bias[nt * 16 + n0];
        float* pw = &hT[(nt * 16 + n0) * MSTR];
        #pragma unroll
        for (int r = 0; r < 4; ++r) {
          const int m = mrow0 + r;
          const int s = s0 - 3 + m;
          const bool vld = (s >= 0 && s < SEQ);
          pw[m] = vld ? (acc[nt][r] + bn) : 0.f;
        }
      }
    }
    __syncthreads();   // publish t for next layer / pool
  }

  // ---------------- pool: h3 = relu(agg(t3)); sum owned rows ----------------
  {
    const int c = tid & 127, half = tid >> 7;
    float ps = 0.f;
    const float* pc = &hT[c * MSTR];
    #pragma unroll 1
    for (int r = 0; r < 29; ++r) {
      const int m = 3 + half * 29 + r;
      const int s = s0 + half * 29 + r;
      if (s < SEQ) {
        const float invd = (s == 0 || s == SEQ - 1) ? (1.0f / (2.0f + 1e-8f))
                                                    : (1.0f / (3.0f + 1e-8f));
        ps += fmaxf((pc[m - 1] + pc[m] + pc[m + 1]) * invd, 0.f);
      }
    }
    psum[tid] = ps;
  }
  __syncthreads();
  if (tid < 128)
    partial[((long long)b * GX + gxb) * HID + tid] = psum[tid] + psum[tid + 128];
}

// ---------------------------------------------------------------------------
// Classifier: reduce partials -> mean -> relu(mean@w1+b1)@w2+b2
// ---------------------------------------------------------------------------
__global__ __launch_bounds__(128) void cls_kernel(
    const float* __restrict__ partial,
    const float* __restrict__ w1, const float* __restrict__ b1,
    const float* __restrict__ w2, const float* __restrict__ b2,
    float* __restrict__ out)
{
  __shared__ float ms[128];
  __shared__ float hid[64];
  const int b = blockIdx.x, tid = threadIdx.x;
  float a = 0.f;
  #pragma unroll 1
  for (int g = 0; g < GX; ++g) a += partial[((long long)b * GX + g) * HID + tid];
  ms[tid] = a * (1.0f / 2048.0f);
  __syncthreads();
  if (tid < 64) {
    float h = b1[tid];
    for (int k = 0; k < 128; ++k) h = fmaf(ms[k], w1[k * 64 + tid], h);
    hid[tid] = fmaxf(h, 0.f);
  }
  __syncthreads();
  if (tid < 3) {
    float o = b2[tid];
    for (int k = 0; k < 64; ++k) o = fmaf(hid[k], w2[k * 3 + tid], o);
    out[b * 3 + tid] = o;
  }
}

extern "C" void kernel_launch(void* const* d_in, const int* in_sizes, int n_in,
                              void* d_out, int out_size, void* d_ws, size_t ws_size,
                              hipStream_t stream) {
  (void)in_sizes; (void)n_in; (void)out_size; (void)ws_size;
  const float* x      = (const float*)d_in[0];
  const float* enc_w1 = (const float*)d_in[1];
  const float* enc_b1 = (const float*)d_in[2];
  const float* enc_w2 = (const float*)d_in[3];
  const float* enc_b2 = (const float*)d_in[4];
  const float* gc1_w  = (const float*)d_in[5];
  const float* gc1_b  = (const float*)d_in[6];
  const float* gc2_w  = (const float*)d_in[7];
  const float* gc2_b  = (const float*)d_in[8];
  const float* gc3_w  = (const float*)d_in[9];
  const float* gc3_b  = (const float*)d_in[10];
  const float* cls_w1 = (const float*)d_in[11];
  const float* cls_b1 = (const float*)d_in[12];
  const float* cls_w2 = (const float*)d_in[13];
  const float* cls_b2 = (const float*)d_in[14];

  // workspace layout (rewritten fully every launch — ws is re-poisoned)
  float* Wp      = (float*)d_ws;                 // 16384 f32
  float* bpv     = Wp + 16384;                   // 128 f32
  short* Wfrag   = (short*)(bpv + 128);          // 3 * 2 * 16384 bf16
  float* partial = (float*)(Wfrag + 3 * 2 * 16384);  // NB*GX*HID f32

  prep_fold<<<dim3(17), 256, 0, stream>>>(enc_w2, enc_b2, gc1_w, gc1_b, Wp, bpv);
  prep_shuffle<<<dim3(32, 3), 256, 0, stream>>>(Wp, gc2_w, gc3_w, Wfrag);
  fused_kernel<<<dim3(GX, NB), 256, 0, stream>>>(
      x, enc_w1, enc_b1, Wfrag, bpv, gc2_b, gc3_b, partial);
  cls_kernel<<<dim3(NB), 128, 0, stream>>>(partial, cls_w1, cls_b1, cls_w2, cls_b2,
                                           (float*)d_out);
}